// Round 3
// baseline (230.151 us; speedup 1.0000x reference)
//
#include <hip/hip_runtime.h>

#define B_ 8
#define N_ 1025
#define D_ 768
#define H_ 12
#define NP_ 1024
#define ROWS_ (B_*N_)        /* 8200 */
#define ROWS_PAD_ 8320       /* 65*128 */
#define QKVC_ 2304
#define SCALE_ 0.03608439182435161f  /* 768^-0.5 */
#define LOG2E_ 1.4426950408889634f
#define EPS_ 1e-5f

typedef float f32x4 __attribute__((ext_vector_type(4)));
typedef short s16x8 __attribute__((ext_vector_type(8)));

// async global->LDS, 16B per lane; lds dest must be wave-uniform base + lane*16
#define GLD16(g, l) __builtin_amdgcn_global_load_lds( \
    (const __attribute__((address_space(1))) unsigned int*)(g), \
    (__attribute__((address_space(3))) unsigned int*)(l), 16, 0, 0)

__device__ __forceinline__ float blo(unsigned int u){
  union { unsigned int i; float f; } v; v.i = u << 16; return v.f;
}
__device__ __forceinline__ float bhi(unsigned int u){
  union { unsigned int i; float f; } v; v.i = u & 0xffff0000u; return v.f;
}
__device__ __forceinline__ float bf2f(unsigned short u){
  union { unsigned int i; float f; } v; v.i = ((unsigned int)u) << 16; return v.f;
}
__device__ __forceinline__ unsigned short f2bf(float f){
  union { unsigned int i; float f; } v; v.f = f;
  unsigned int b = v.i;
  b = b + 0x7fffu + ((b >> 16) & 1u);
  return (unsigned short)(b >> 16);
}
// pack two f32 -> two bf16 (round-half-up == RNE except exact ties) in 3 VALU ops
__device__ __forceinline__ unsigned int pkbf2(float a, float b){
  union { float f; unsigned int i; } ua, ub;
  ua.f = a; ub.f = b;
  return __builtin_amdgcn_perm(ub.i + 0x8000u, ua.i + 0x8000u, 0x07060302u);
}
// HW pack: dst.lo = bf16(a), dst.hi = bf16(b) (RNE), 1 VALU op (guide T12 recipe)
__device__ __forceinline__ unsigned int cvtpk(float a, float b){
  unsigned int r;
  asm("v_cvt_pk_bf16_f32 %0, %1, %2" : "=v"(r) : "v"(a), "v"(b));
  return r;
}

// ---------------- fused weight transposes (768 x N) fp32 -> (N x 768) bf16 ----
__global__ __launch_bounds__(256) void transpose_f2b2(
    const float* __restrict__ w1, unsigned short* __restrict__ d1,
    const float* __restrict__ w2, unsigned short* __restrict__ d2) {
  __shared__ unsigned short tile[32][33];
  int bx = blockIdx.x;
  const float* src; unsigned short* dst; int N, nb;
  if (bx < 72) { src = w1; dst = d1; N = QKVC_; nb = bx * 32; }
  else         { src = w2; dst = d2; N = D_;    nb = (bx - 72) * 32; }
  int kb = blockIdx.y * 32;
  int tx = threadIdx.x & 31, ty = threadIdx.x >> 5;  // 32 x 8
  #pragma unroll
  for (int i = 0; i < 4; i++) {
    int r = ty + i * 8;
    tile[r][tx] = f2bf(src[(size_t)(kb + r) * N + nb + tx]);
  }
  __syncthreads();
  #pragma unroll
  for (int i = 0; i < 4; i++) {
    int r = ty + i * 8;
    dst[(size_t)(nb + r) * D_ + kb + tx] = tile[tx][r];
  }
}

// ---------------- layernorm: x[8200][768] fp32 -> xn bf16 (shuffle-reduce) ----
__global__ __launch_bounds__(256) void layernorm_k(
    const float* __restrict__ x, const float* __restrict__ w,
    const float* __restrict__ b, unsigned short* __restrict__ xn) {
  int row = blockIdx.x;
  int t = threadIdx.x;
  const float* xr = x + (size_t)row * D_;
  float v0 = xr[t], v1 = xr[t + 256], v2 = xr[t + 512];
  float s = v0 + v1 + v2;
  float q = v0 * v0 + v1 * v1 + v2 * v2;
  #pragma unroll
  for (int off = 32; off > 0; off >>= 1) {
    s += __shfl_xor(s, off, 64);
    q += __shfl_xor(q, off, 64);
  }
  __shared__ float r8[8];
  int wv = t >> 6;
  if ((t & 63) == 0) { r8[wv] = s; r8[4 + wv] = q; }
  __syncthreads();
  s = r8[0] + r8[1] + r8[2] + r8[3];
  q = r8[4] + r8[5] + r8[6] + r8[7];
  float mean = s * (1.0f / 768.0f);
  float var = q * (1.0f / 768.0f) - mean * mean;
  var = var < 0.f ? 0.f : var;
  float rstd = rsqrtf(var + EPS_);
  unsigned short* yr = xn + (size_t)row * D_;
  yr[t]       = f2bf((v0 - mean) * rstd * w[t]       + b[t]);
  yr[t + 256] = f2bf((v1 - mean) * rstd * w[t + 256] + b[t + 256]);
  yr[t + 512] = f2bf((v2 - mean) * rstd * w[t + 512] + b[t + 512]);
}

// ---------------- GEMM: C[M][N] = A[M][K] * Bt[N][K]^T (+bias)
// 128x128 tile, 256 thr / 4 waves (2Mx2N), wave tile 64x64, BK=64.
// Double-buffered LDS = 64KB (2 blocks/CU co-resident -> TLP preserved).
// Minimum-2-phase pipeline: ONE vmcnt(0)+s_barrier per K-tile; next tile's 8
// global_load_lds issued BEFORE compute so they overlap the full MFMA phase.
// T2 swizzle: [128 rows][64 k] = 8x16B granules/row; LDS linear, global source
// k-granule = slot ^ (row&7); fragment read granule (ks*4+quad)^(m16&7) ->
// every granule-base hit by exactly 2 lanes = free. T1 bijective XCD swizzle.
// NOTE (r2 post-mortem): at 128^2 the per-K-step L2 operand traffic (64KB/CU)
// bounds MfmaUtil at ~27%; we measure 24%. Near structural ceiling for this tile.
template <bool OF32>
__global__ __launch_bounds__(256) void gemm_bt(
    const unsigned short* __restrict__ A, const unsigned short* __restrict__ Bt,
    void* __restrict__ Cv, const float* __restrict__ bias,
    int Mvalid, int Nn, int Kk) {
  __shared__ short sh[32768];  // 64KB: As[2][8192] | Bs[2][8192]; reused as C-stage
  int t = threadIdx.x;
  int lane = t & 63, w = t >> 6;
  int m16 = lane & 15, quad = lane >> 4;

  // bijective XCD swizzle (m204): consecutive wg on one XCD share the A panel
  int nwg = gridDim.x;
  int nbx = Nn >> 7;
  int id = blockIdx.x;
  int qq = nwg >> 3, rr = nwg & 7;
  int xcd = id & 7, off = id >> 3;
  int wg = (xcd < rr ? xcd * (qq + 1) : rr * (qq + 1) + (xcd - rr) * qq) + off;
  int bx = wg % nbx, by = wg / nbx;
  int bm = by * 128, bn = bx * 128;

  int wm = (w & 1) * 64, wn = (w >> 1) * 64;

  f32x4 acc[4][4];
  #pragma unroll
  for (int i = 0; i < 4; i++)
    #pragma unroll
    for (int j = 0; j < 4; j++) acc[i][j] = (f32x4){0.f, 0.f, 0.f, 0.f};

  // staging: thread owns granules g = t + c*256 (c=0..3) of each 16KB tile.
  // LDS dest linear (granule g at shorts g*8); global src pre-swizzled.
  const unsigned short* aP[4];
  const unsigned short* bP[4];
  #pragma unroll
  for (int c = 0; c < 4; c++) {
    int g = t + c * 256;
    int row = g >> 3, slot = g & 7;
    aP[c] = A  + (size_t)(bm + row) * Kk + ((slot ^ (row & 7)) * 8);
    bP[c] = Bt + (size_t)(bn + row) * Kk + ((slot ^ (row & 7)) * 8);
  }

  int KS = Kk >> 6;  // 12
  int cur = 0;
  // prologue: stage tile 0 into buf 0
  #pragma unroll
  for (int c = 0; c < 4; c++) GLD16(aP[c], sh + (t + c * 256) * 8);
  #pragma unroll
  for (int c = 0; c < 4; c++) GLD16(bP[c], sh + 16384 + (t + c * 256) * 8);

  for (int kt = 0; kt < KS; kt++) {
    // wait own 8 loads of tile kt; barrier -> ALL waves' tile-kt data in LDS,
    // and all waves done reading buf^1 (last read in iter kt-1) -> safe to stage.
    asm volatile("s_waitcnt vmcnt(0)" ::: "memory");
    __builtin_amdgcn_s_barrier();
    if (kt + 1 < KS) {
      int nb2 = (cur ^ 1) * 8192;
      int ko = (kt + 1) * 64;
      #pragma unroll
      for (int c = 0; c < 4; c++) GLD16(aP[c] + ko, sh + nb2 + (t + c * 256) * 8);
      #pragma unroll
      for (int c = 0; c < 4; c++) GLD16(bP[c] + ko, sh + 16384 + nb2 + (t + c * 256) * 8);
    }
    const short* sa = sh + cur * 8192;
    const short* sb = sh + 16384 + cur * 8192;
    #pragma unroll
    for (int ks = 0; ks < 2; ks++) {
      int so = ((ks * 4 + quad) ^ (m16 & 7)) * 8;
      s16x8 af[4], bfr[4];
      #pragma unroll
      for (int i = 0; i < 4; i++) {
        af[i]  = *(const s16x8*)(sa + (wm + i * 16 + m16) * 64 + so);
        bfr[i] = *(const s16x8*)(sb + (wn + i * 16 + m16) * 64 + so);
      }
      __builtin_amdgcn_s_setprio(1);
      #pragma unroll
      for (int i = 0; i < 4; i++)
        #pragma unroll
        for (int j = 0; j < 4; j++)
          acc[i][j] = __builtin_amdgcn_mfma_f32_16x16x32_bf16(af[i], bfr[j], acc[i][j], 0, 0, 0);
      __builtin_amdgcn_s_setprio(0);
    }
    cur ^= 1;
  }
  __syncthreads();  // all LDS reads done; no loads in flight (last iter staged none)

  // ---- epilogue: stage C through LDS, coalesced stores
  if (!OF32) {
    unsigned short* C = (unsigned short*)Cv;
    #pragma unroll
    for (int j = 0; j < 4; j++) {
      int col = wn + j * 16 + m16;
      #pragma unroll
      for (int i = 0; i < 4; i++)
        #pragma unroll
        for (int r = 0; r < 4; r++)
          sh[(wm + i * 16 + quad * 4 + r) * 128 + col] = (short)f2bf(acc[i][j][r]);
    }
    __syncthreads();
    #pragma unroll
    for (int c = 0; c < 8; c++) {
      int idx = c * 256 + t;
      int row = idx >> 4, col = (idx & 15) * 8;
      if (bm + row < Mvalid)
        *(uint4*)(&C[(size_t)(bm + row) * Nn + bn + col]) = *(const uint4*)(&sh[row * 128 + col]);
    }
  } else {
    float* Cf = (float*)Cv;
    float* shf = (float*)sh;  // 128 x 128 f32 = 64KB, single pass
    #pragma unroll
    for (int j = 0; j < 4; j++) {
      int col = wn + j * 16 + m16;
      float bv = bias ? bias[bn + col] : 0.f;
      #pragma unroll
      for (int i = 0; i < 4; i++)
        #pragma unroll
        for (int r = 0; r < 4; r++)
          shf[(wm + i * 16 + quad * 4 + r) * 128 + col] = acc[i][j][r] + bv;
    }
    __syncthreads();
    #pragma unroll
    for (int c = 0; c < 16; c++) {
      int idx = c * 256 + t;
      int row = idx >> 5, col = (idx & 31) * 4;
      if (bm + row < Mvalid)
        *(float4*)(&Cf[(size_t)(bm + row) * Nn + bn + col]) =
            *(const float4*)(&shf[row * 128 + col]);
    }
  }
}

// ---------------- block-wide sum helper ----------------
__device__ __forceinline__ float block_sum(float v, float* red) {
  int t = threadIdx.x;
  red[t] = v;
  __syncthreads();
  for (int st = 128; st > 0; st >>= 1) {
    if (t < st) red[t] += red[t + st];
    __syncthreads();
  }
  float r = red[0];
  __syncthreads();
  return r;
}

// ---------------- CLS-row attention (row 0 of each (b,h)) ----------------
__global__ __launch_bounds__(256) void attn_cls(
    const unsigned short* __restrict__ qkv, const float* __restrict__ canny,
    const float* __restrict__ noise, unsigned short* __restrict__ attn_out) {
  int bh = blockIdx.x;
  int b = bh / H_, h = bh % H_;
  int t = threadIdx.x;
  __shared__ float s[N_];
  __shared__ float red[256];
  __shared__ float q[64];
  __shared__ float pvred[64 * 33];  // [dim][group], +1 pad -> conflict-free

  if (t < 64) q[t] = bf2f(qkv[(size_t)(b * N_) * QKVC_ + h * 64 + t]);
  __syncthreads();

  // QK: vectorized uint4 loads (8 x 16B per key row)
  for (int j = t; j < N_; j += 256) {
    const unsigned short* krow = qkv + (size_t)(b * N_ + j) * QKVC_ + D_ + h * 64;
    float dot = 0.f;
    #pragma unroll
    for (int c = 0; c < 8; c++) {
      uint4 kk = *(const uint4*)(krow + c * 8);
      dot += q[c*8+0]*blo(kk.x) + q[c*8+1]*bhi(kk.x)
           + q[c*8+2]*blo(kk.y) + q[c*8+3]*bhi(kk.y)
           + q[c*8+4]*blo(kk.z) + q[c*8+5]*bhi(kk.z)
           + q[c*8+6]*blo(kk.w) + q[c*8+7]*bhi(kk.w);
    }
    s[j] = dot * SCALE_;
  }
  float cp = 0.f, npp = 0.f;
  for (int j = t; j < NP_; j += 256) {
    cp  += canny[b * NP_ + j] + 1.0f;
    npp += noise[b * NP_ + j];
  }
  float csum = block_sum(cp, red);
  float nsum = block_sum(npp, red);
  float e1 = 0.f;
  for (int j = t; j < N_; j += 256) if (j >= 1) e1 += __expf(s[j]);
  float sum1 = block_sum(e1, red);
  for (int j = t; j < N_; j += 256) {
    if (j >= 1) {
      s[j] = __expf(s[j]) / sum1
           + (canny[b * NP_ + j - 1] + 1.0f) / csum
           + noise[b * NP_ + j - 1] / nsum;
    }
  }
  __syncthreads();
  float e2 = 0.f;
  for (int j = t; j < N_; j += 256) { float e = __expf(s[j]); s[j] = e; e2 += e; }
  float sum2 = block_sum(e2, red);
  // PV: thread owns dim-octet o (8 dims), strides 32 rows -> 1 uint4 load/iter
  {
    int o = t & 7, g = t >> 3;
    float a[8] = {0.f, 0.f, 0.f, 0.f, 0.f, 0.f, 0.f, 0.f};
    for (int j = g; j < N_; j += 32) {
      float sv = s[j];
      uint4 vv = *(const uint4*)(qkv + (size_t)(b * N_ + j) * QKVC_ + 2 * D_ + h * 64 + o * 8);
      a[0] += sv * blo(vv.x); a[1] += sv * bhi(vv.x);
      a[2] += sv * blo(vv.y); a[3] += sv * bhi(vv.y);
      a[4] += sv * blo(vv.z); a[5] += sv * bhi(vv.z);
      a[6] += sv * blo(vv.w); a[7] += sv * bhi(vv.w);
    }
    #pragma unroll
    for (int i = 0; i < 8; i++) pvred[(o * 8 + i) * 33 + g] = a[i];
  }
  __syncthreads();
  if (t < 64) {
    float acc = 0.f;
    #pragma unroll
    for (int u = 0; u < 32; u++) acc += pvred[t * 33 + u];
    attn_out[(size_t)(b * N_) * D_ + h * 64 + t] = f2bf(acc / sum2);
  }
}

// ---------------- main attention (MFMA): rows 1..1024, 128 rows/block ----------------
// S^T = K·Q^T via mfma; P exits in PV A-layout via b64 LDS writes; V^T staged
// per tile. SCALE*log2e pre-folded into Q fragments -> P = exp2(s) = bare
// v_exp_f32 (saves 32 v_mul/thread/jt vs __expf). P-pack via v_cvt_pk_bf16_f32
// (1 VALU per 2 vals vs 3). l computed via ones-MFMA. K/V register-prefetched
// one tile ahead. T5 setprio around MFMA clusters (blocks at different phases
// on a CU -> m191-positive regime). 16 unmasked tiles + key-1024 tail.
__global__ __launch_bounds__(256) void attn_main(
    const unsigned short* __restrict__ qkv, unsigned short* __restrict__ attn_out) {
  int id = blockIdx.x;
  int tile = id / 96;
  int rem = id % 96;
  int h = rem >> 3;
  int b = rem & 7;
  int t = threadIdx.x;
  int lane = t & 63, w = t >> 6;
  int m16 = lane & 15, quad = lane >> 4;

  __shared__ short ps[128 * 72];        // Q staging, then P tiles [row][key]
  __shared__ short ks[64 * 72];         // K tile [key][hd]
  __shared__ unsigned int vs[64 * 36];  // V^T tile [dim][keypair]
  __shared__ float tailbuf[256];        // k1024[64] | v1024[64] | p[128]

  int qbase = 1 + tile * 128;

  // ---- stage Q (each wave stages exactly its own 32 rows)
  {
    int r = t >> 1, seg = (t & 1) * 32;
    const uint4* src = (const uint4*)(qkv + (size_t)(b * N_ + qbase + r) * QKVC_ + h * 64 + seg);
    uint4 u0 = src[0], u1 = src[1], u2 = src[2], u3 = src[3];
    *(uint4*)(&ps[r * 72 + seg])      = u0;
    *(uint4*)(&ps[r * 72 + seg + 8])  = u1;
    *(uint4*)(&ps[r * 72 + seg + 16]) = u2;
    *(uint4*)(&ps[r * 72 + seg + 24]) = u3;
  }
  // ---- Q B-operand fragments, pre-scaled by SCALE_*LOG2E_ (P = exp2(s) later)
  s16x8 qb[2][2];
  #pragma unroll
  for (int nt = 0; nt < 2; nt++)
    #pragma unroll
    for (int ks_ = 0; ks_ < 2; ks_++) {
      qb[nt][ks_] = *(const s16x8*)(&ps[(w * 32 + nt * 16 + m16) * 72 + ks_ * 32 + quad * 8]);
      unsigned int* u = (unsigned int*)&qb[nt][ks_];
      #pragma unroll
      for (int i = 0; i < 4; i++)
        u[i] = cvtpk(blo(u[i]) * (SCALE_ * LOG2E_), bhi(u[i]) * (SCALE_ * LOG2E_));
    }
  // ones fragment for row-sum MFMA
  s16x8 vone;
  #pragma unroll
  for (int i = 0; i < 8; i++) vone[i] = (short)0x3F80;

  f32x4 oacc[2][4], lacc[2];
  #pragma unroll
  for (int mt = 0; mt < 2; mt++) {
    lacc[mt] = (f32x4){0.f, 0.f, 0.f, 0.f};
    #pragma unroll
    for (int dt = 0; dt < 4; dt++) oacc[mt][dt] = (f32x4){0.f, 0.f, 0.f, 0.f};
  }

  // ---- prefetch addressing
  int kkey = t >> 2, kseg = (t & 3) * 16;
  const unsigned short* kbase = qkv + (size_t)(b * N_) * QKVC_ + D_ + h * 64;
  int vp2 = t & 31, vseg = t >> 5;
  const unsigned short* vbase = qkv + (size_t)(b * N_) * QKVC_ + 2 * D_ + h * 64 + vseg * 8;
  uint4 kr0, kr1, vr0, vr1;
  {
    const uint4* ksrc = (const uint4*)(kbase + (size_t)kkey * QKVC_ + kseg);
    kr0 = ksrc[0]; kr1 = ksrc[1];
    vr0 = *(const uint4*)(vbase + (size_t)(2 * vp2) * QKVC_);
    vr1 = *(const uint4*)(vbase + (size_t)(2 * vp2 + 1) * QKVC_);
  }

  for (int jt = 0; jt < 16; jt++) {
    __syncthreads();  // prior QK(ks)/PV(vs) reads complete
    // ---- write prefetched K tile [key][hd]
    *(uint4*)(&ks[kkey * 72 + kseg])     = kr0;
    *(uint4*)(&ks[kkey * 72 + kseg + 8]) = kr1;
    // ---- write prefetched V^T tile [dim][keypair] (perm pack)
    {
      const unsigned int* vaw = (const unsigned int*)&vr0;
      const unsigned int* vbw = (const unsigned int*)&vr1;
      #pragma unroll
      for (int i = 0; i < 4; i++) {
        vs[(vseg * 8 + 2 * i)     * 36 + vp2] = __builtin_amdgcn_perm(vbw[i], vaw[i], 0x05040100u);
        vs[(vseg * 8 + 2 * i + 1) * 36 + vp2] = __builtin_amdgcn_perm(vbw[i], vaw[i], 0x07060302u);
      }
    }
    __syncthreads();  // staging visible (no global loads in flight here)
    // ---- issue next tile's loads; they overlap QK+exp, drain at next barrier
    if (jt < 15) {
      int j0 = (jt + 1) * 64;
      const uint4* ksrc = (const uint4*)(kbase + (size_t)(j0 + kkey) * QKVC_ + kseg);
      kr0 = ksrc[0]; kr1 = ksrc[1];
      vr0 = *(const uint4*)(vbase + (size_t)(j0 + 2 * vp2) * QKVC_);
      vr1 = *(const uint4*)(vbase + (size_t)(j0 + 2 * vp2 + 1) * QKVC_);
    }
    // ---- QK: S^T[key][qrow] per wave: 4 key-tiles x 2 row-tiles
    f32x4 sacc[4][2];
    __builtin_amdgcn_s_setprio(1);
    #pragma unroll
    for (int kt = 0; kt < 4; kt++) {
      s16x8 ka0 = *(const s16x8*)(&ks[(kt * 16 + m16) * 72 + quad * 8]);
      s16x8 ka1 = *(const s16x8*)(&ks[(kt * 16 + m16) * 72 + 32 + quad * 8]);
      #pragma unroll
      for (int nt = 0; nt < 2; nt++) {
        f32x4 s = (f32x4){0.f, 0.f, 0.f, 0.f};
        s = __builtin_amdgcn_mfma_f32_16x16x32_bf16(ka0, qb[nt][0], s, 0, 0, 0);
        s = __builtin_amdgcn_mfma_f32_16x16x32_bf16(ka1, qb[nt][1], s, 0, 0, 0);
        sacc[kt][nt] = s;
      }
    }
    __builtin_amdgcn_s_setprio(0);
    // ---- P = exp2(s) (scale+log2e pre-folded); cvt_pk -> b64 write
    #pragma unroll
    for (int kt = 0; kt < 4; kt++) {
      #pragma unroll
      for (int nt = 0; nt < 2; nt++) {
        f32x4 s = sacc[kt][nt];
        float p0 = exp2f(s[0]);
        float p1 = exp2f(s[1]);
        float p2 = exp2f(s[2]);
        float p3 = exp2f(s[3]);
        uint2 pk = {cvtpk(p0, p1), cvtpk(p2, p3)};
        *(uint2*)(&ps[(w * 32 + nt * 16 + m16) * 72 + kt * 16 + quad * 4]) = pk;
      }
    }
    __syncthreads();  // ps visible; prefetch loads drained here (overlapped)
    // ---- PV: O += P·V ; l += P·1 (C-layout row-sums)
    s16x8 pa[2][2];
    #pragma unroll
    for (int mt = 0; mt < 2; mt++)
      #pragma unroll
      for (int ks_ = 0; ks_ < 2; ks_++)
        pa[mt][ks_] = *(const s16x8*)(&ps[(w * 32 + mt * 16 + m16) * 72 + ks_ * 32 + quad * 8]);
    const short* vss = (const short*)vs;
    __builtin_amdgcn_s_setprio(1);
    #pragma unroll
    for (int dt = 0; dt < 4; dt++) {
      s16x8 vb0 = *(const s16x8*)(&vss[(dt * 16 + m16) * 72 + quad * 8]);
      s16x8 vb1 = *(const s16x8*)(&vss[(dt * 16 + m16) * 72 + 32 + quad * 8]);
      #pragma unroll
      for (int mt = 0; mt < 2; mt++) {
        oacc[mt][dt] = __builtin_amdgcn_mfma_f32_16x16x32_bf16(pa[mt][0], vb0, oacc[mt][dt], 0, 0, 0);
        oacc[mt][dt] = __builtin_amdgcn_mfma_f32_16x16x32_bf16(pa[mt][1], vb1, oacc[mt][dt], 0, 0, 0);
      }
    }
    #pragma unroll
    for (int mt = 0; mt < 2; mt++) {
      lacc[mt] = __builtin_amdgcn_mfma_f32_16x16x32_bf16(pa[mt][0], vone, lacc[mt], 0, 0, 0);
      lacc[mt] = __builtin_amdgcn_mfma_f32_16x16x32_bf16(pa[mt][1], vone, lacc[mt], 0, 0, 0);
    }
    __builtin_amdgcn_s_setprio(0);
  }
  // ---- tail: key 1024 (q fragments pre-scaled -> p = exp2(d))
  if (t < 64)       tailbuf[t]             = bf2f(qkv[(size_t)(b * N_ + 1024) * QKVC_ + D_     + h * 64 + t]);
  else if (t < 128) tailbuf[64 + (t - 64)] = bf2f(qkv[(size_t)(b * N_ + 1024) * QKVC_ + 2 * D_ + h * 64 + (t - 64)]);
  __syncthreads();
  #pragma unroll
  for (int nt = 0; nt < 2; nt++) {
    float d = 0.f;
    #pragma unroll
    for (int jj = 0; jj < 8; jj++) {
      d += bf2f((unsigned short)qb[nt][0][jj]) * tailbuf[quad * 8 + jj];
      d += bf2f((unsigned short)qb[nt][1][jj]) * tailbuf[32 + quad * 8 + jj];
    }
    d += __shfl_xor(d, 16, 64);
    d += __shfl_xor(d, 32, 64);
    float p = exp2f(d);
    if (quad == 0) tailbuf[128 + w * 32 + nt * 16 + m16] = p;
  }
  __syncthreads();
  #pragma unroll
  for (int mt = 0; mt < 2; mt++)
    #pragma unroll
    for (int r = 0; r < 4; r++) {
      float pr = tailbuf[128 + w * 32 + mt * 16 + quad * 4 + r];
      lacc[mt][r] += pr;
      #pragma unroll
      for (int dt = 0; dt < 4; dt++)
        oacc[mt][dt][r] += pr * tailbuf[64 + dt * 16 + m16];
    }
  // ---- normalize + store (O layout: row=quad*4+r+mt*16, dim=dt*16+m16)
  #pragma unroll
  for (int mt = 0; mt < 2; mt++) {
    float rinv[4];
    #pragma unroll
    for (int r = 0; r < 4; r++) rinv[r] = 1.0f / lacc[mt][r];
    #pragma unroll
    for (int dt = 0; dt < 4; dt++) {
      #pragma unroll
      for (int r = 0; r < 4; r++) {
        int grow = b * N_ + qbase + w * 32 + mt * 16 + quad * 4 + r;
        attn_out[(size_t)grow * D_ + h * 64 + dt * 16 + m16] = f2bf(oacc[mt][dt][r] * rinv[r]);
      }
    }
  }
}

// ---------------- launch ----------------
extern "C" void kernel_launch(void* const* d_in, const int* in_sizes, int n_in,
                              void* d_out, int out_size, void* d_ws, size_t ws_size,
                              hipStream_t stream) {
  (void)in_sizes; (void)n_in; (void)out_size; (void)ws_size;
  const float* x     = (const float*)d_in[0];
  const float* canny = (const float*)d_in[1];
  const float* noise = (const float*)d_in[2];
  const float* lnw   = (const float*)d_in[3];
  const float* lnb   = (const float*)d_in[4];
  const float* wqkv  = (const float*)d_in[5];
  const float* wout  = (const float*)d_in[6];
  const float* bout  = (const float*)d_in[7];
  float* out = (float*)d_out;
  char* ws = (char*)d_ws;

  unsigned short* xn    = (unsigned short*)(ws);              // 8320*768 bf16 (reused as attn_out)
  unsigned short* wqkvT = (unsigned short*)(ws + 12779520);   // 2304*768
  unsigned short* woutT = (unsigned short*)(ws + 16318464);   // 768*768
  unsigned short* qkv   = (unsigned short*)(ws + 17498112);   // 8200*2304

  transpose_f2b2<<<dim3(96, 24), 256, 0, stream>>>(wqkv, wqkvT, wout, woutT);
  layernorm_k<<<dim3(ROWS_), 256, 0, stream>>>(x, lnw, lnb, xn);
  gemm_bt<false><<<dim3((QKVC_ / 128) * (ROWS_PAD_ / 128)), 256, 0, stream>>>(
      xn, wqkvT, (void*)qkv, nullptr, ROWS_, QKVC_, D_);
  attn_cls<<<dim3(B_ * H_), 256, 0, stream>>>(qkv, canny, noise, xn);
  attn_main<<<dim3(8 * H_ * B_), 256, 0, stream>>>(qkv, xn);
  gemm_bt<true><<<dim3((D_ / 128) * (ROWS_PAD_ / 128)), 256, 0, stream>>>(
      xn, woutT, (void*)out, bout, ROWS_, D_, D_);
}

// Round 5
// 206.998 us; speedup vs baseline: 1.1119x; 1.1119x over previous
//
#include <hip/hip_runtime.h>

#define B_ 8
#define N_ 1025
#define D_ 768
#define H_ 12
#define NP_ 1024
#define ROWS_ (B_*N_)        /* 8200 */
#define ROWS_PAD_ 8320       /* 65*128 */
#define QKVC_ 2304
#define SCALE_ 0.03608439182435161f  /* 768^-0.5 */
#define EPS_ 1e-5f

typedef float f32x4 __attribute__((ext_vector_type(4)));
typedef short s16x8 __attribute__((ext_vector_type(8)));

// async global->LDS, 16B per lane; lds dest must be wave-uniform base + lane*16
#define GLD16(g, l) __builtin_amdgcn_global_load_lds( \
    (const __attribute__((address_space(1))) unsigned int*)(g), \
    (__attribute__((address_space(3))) unsigned int*)(l), 16, 0, 0)

__device__ __forceinline__ float blo(unsigned int u){
  union { unsigned int i; float f; } v; v.i = u << 16; return v.f;
}
__device__ __forceinline__ float bhi(unsigned int u){
  union { unsigned int i; float f; } v; v.i = u & 0xffff0000u; return v.f;
}
__device__ __forceinline__ float bf2f(unsigned short u){
  union { unsigned int i; float f; } v; v.i = ((unsigned int)u) << 16; return v.f;
}
__device__ __forceinline__ unsigned short f2bf(float f){
  union { unsigned int i; float f; } v; v.f = f;
  unsigned int b = v.i;
  b = b + 0x7fffu + ((b >> 16) & 1u);
  return (unsigned short)(b >> 16);
}
// pack two f32 -> two bf16 (round-half-up, bit-identical to f2bf pairs), 3 VALU
__device__ __forceinline__ unsigned int pkbf2(float a, float b){
  union { float f; unsigned int i; } ua, ub;
  ua.f = a; ub.f = b;
  return __builtin_amdgcn_perm(ub.i + 0x8000u, ua.i + 0x8000u, 0x07060302u);
}

// ---------------- fused weight transposes (768 x N) fp32 -> (N x 768) bf16 ----
__global__ __launch_bounds__(256) void transpose_f2b2(
    const float* __restrict__ w1, unsigned short* __restrict__ d1,
    const float* __restrict__ w2, unsigned short* __restrict__ d2) {
  __shared__ unsigned short tile[32][33];
  int bx = blockIdx.x;
  const float* src; unsigned short* dst; int N, nb;
  if (bx < 72) { src = w1; dst = d1; N = QKVC_; nb = bx * 32; }
  else         { src = w2; dst = d2; N = D_;    nb = (bx - 72) * 32; }
  int kb = blockIdx.y * 32;
  int tx = threadIdx.x & 31, ty = threadIdx.x >> 5;  // 32 x 8
  #pragma unroll
  for (int i = 0; i < 4; i++) {
    int r = ty + i * 8;
    tile[r][tx] = f2bf(src[(size_t)(kb + r) * N + nb + tx]);
  }
  __syncthreads();
  #pragma unroll
  for (int i = 0; i < 4; i++) {
    int r = ty + i * 8;
    dst[(size_t)(nb + r) * D_ + kb + tx] = tile[tx][r];
  }
}

// ---------------- layernorm: x[8200][768] fp32 -> xn bf16 ----
// 192 thr/block (3 waves), float4 loads (16B/lane, G13), uint2 bf16 stores.
__global__ __launch_bounds__(192) void layernorm_k(
    const float* __restrict__ x, const float* __restrict__ w,
    const float* __restrict__ b, unsigned short* __restrict__ xn) {
  int row = blockIdx.x;
  int t = threadIdx.x;
  float4 v = ((const float4*)(x + (size_t)row * D_))[t];
  float s = v.x + v.y + v.z + v.w;
  float q = v.x * v.x + v.y * v.y + v.z * v.z + v.w * v.w;
  #pragma unroll
  for (int off = 32; off > 0; off >>= 1) {
    s += __shfl_xor(s, off, 64);
    q += __shfl_xor(q, off, 64);
  }
  __shared__ float r6[6];
  int wv = t >> 6;
  if ((t & 63) == 0) { r6[wv] = s; r6[3 + wv] = q; }
  __syncthreads();
  s = r6[0] + r6[1] + r6[2];
  q = r6[3] + r6[4] + r6[5];
  float mean = s * (1.0f / 768.0f);
  float var = q * (1.0f / 768.0f) - mean * mean;
  var = var < 0.f ? 0.f : var;
  float rstd = rsqrtf(var + EPS_);
  float4 wv4 = ((const float4*)w)[t];
  float4 bv4 = ((const float4*)b)[t];
  float o0 = (v.x - mean) * rstd * wv4.x + bv4.x;
  float o1 = (v.y - mean) * rstd * wv4.y + bv4.y;
  float o2 = (v.z - mean) * rstd * wv4.z + bv4.z;
  float o3 = (v.w - mean) * rstd * wv4.w + bv4.w;
  uint2 pk = {pkbf2(o0, o1), pkbf2(o2, o3)};
  *(uint2*)(xn + (size_t)row * D_ + t * 4) = pk;
}

// ---------------- GEMM: C[M][N] = A[M][K] * Bt[N][K]^T (+bias)
// 128x128 tile, 256 thr / 4 waves (2Mx2N), wave tile 64x64, BK=64.
// Double-buffered LDS = 64KB (2 blocks/CU co-resident -> TLP preserved).
// Minimum-2-phase pipeline: ONE vmcnt(0)+s_barrier per K-tile; next tile's 8
// global_load_lds issued BEFORE compute so they overlap the full MFMA phase.
// T2 swizzle: [128 rows][64 k] = 8x16B granules/row; LDS linear, global source
// k-granule = slot ^ (row&7); fragment read granule (ks*4+quad)^(m16&7) ->
// every granule-base hit by exactly 2 lanes = free. T1 bijective XCD swizzle.
// NOTE (r2 post-mortem): at 128^2 the per-K-step L2 operand traffic (64KB/CU)
// bounds MfmaUtil at ~27%; we measure 24%. Near structural ceiling for this tile.
template <bool OF32>
__global__ __launch_bounds__(256) void gemm_bt(
    const unsigned short* __restrict__ A, const unsigned short* __restrict__ Bt,
    void* __restrict__ Cv, const float* __restrict__ bias,
    int Mvalid, int Nn, int Kk) {
  __shared__ short sh[32768];  // 64KB: As[2][8192] | Bs[2][8192]; reused as C-stage
  int t = threadIdx.x;
  int lane = t & 63, w = t >> 6;
  int m16 = lane & 15, quad = lane >> 4;

  // bijective XCD swizzle (m204): consecutive wg on one XCD share the A panel
  int nwg = gridDim.x;
  int nbx = Nn >> 7;
  int id = blockIdx.x;
  int qq = nwg >> 3, rr = nwg & 7;
  int xcd = id & 7, off = id >> 3;
  int wg = (xcd < rr ? xcd * (qq + 1) : rr * (qq + 1) + (xcd - rr) * qq) + off;
  int bx = wg % nbx, by = wg / nbx;
  int bm = by * 128, bn = bx * 128;

  int wm = (w & 1) * 64, wn = (w >> 1) * 64;

  f32x4 acc[4][4];
  #pragma unroll
  for (int i = 0; i < 4; i++)
    #pragma unroll
    for (int j = 0; j < 4; j++) acc[i][j] = (f32x4){0.f, 0.f, 0.f, 0.f};

  // staging: thread owns granules g = t + c*256 (c=0..3) of each 16KB tile.
  // LDS dest linear (granule g at shorts g*8); global src pre-swizzled.
  const unsigned short* aP[4];
  const unsigned short* bP[4];
  #pragma unroll
  for (int c = 0; c < 4; c++) {
    int g = t + c * 256;
    int row = g >> 3, slot = g & 7;
    aP[c] = A  + (size_t)(bm + row) * Kk + ((slot ^ (row & 7)) * 8);
    bP[c] = Bt + (size_t)(bn + row) * Kk + ((slot ^ (row & 7)) * 8);
  }

  int KS = Kk >> 6;  // 12
  int cur = 0;
  // prologue: stage tile 0 into buf 0
  #pragma unroll
  for (int c = 0; c < 4; c++) GLD16(aP[c], sh + (t + c * 256) * 8);
  #pragma unroll
  for (int c = 0; c < 4; c++) GLD16(bP[c], sh + 16384 + (t + c * 256) * 8);

  for (int kt = 0; kt < KS; kt++) {
    // wait own 8 loads of tile kt; barrier -> ALL waves' tile-kt data in LDS,
    // and all waves done reading buf^1 (last read in iter kt-1) -> safe to stage.
    asm volatile("s_waitcnt vmcnt(0)" ::: "memory");
    __builtin_amdgcn_s_barrier();
    if (kt + 1 < KS) {
      int nb2 = (cur ^ 1) * 8192;
      int ko = (kt + 1) * 64;
      #pragma unroll
      for (int c = 0; c < 4; c++) GLD16(aP[c] + ko, sh + nb2 + (t + c * 256) * 8);
      #pragma unroll
      for (int c = 0; c < 4; c++) GLD16(bP[c] + ko, sh + 16384 + nb2 + (t + c * 256) * 8);
    }
    const short* sa = sh + cur * 8192;
    const short* sb = sh + 16384 + cur * 8192;
    #pragma unroll
    for (int ks = 0; ks < 2; ks++) {
      int so = ((ks * 4 + quad) ^ (m16 & 7)) * 8;
      s16x8 af[4], bfr[4];
      #pragma unroll
      for (int i = 0; i < 4; i++) {
        af[i]  = *(const s16x8*)(sa + (wm + i * 16 + m16) * 64 + so);
        bfr[i] = *(const s16x8*)(sb + (wn + i * 16 + m16) * 64 + so);
      }
      __builtin_amdgcn_s_setprio(1);
      #pragma unroll
      for (int i = 0; i < 4; i++)
        #pragma unroll
        for (int j = 0; j < 4; j++)
          acc[i][j] = __builtin_amdgcn_mfma_f32_16x16x32_bf16(af[i], bfr[j], acc[i][j], 0, 0, 0);
      __builtin_amdgcn_s_setprio(0);
    }
    cur ^= 1;
  }
  __syncthreads();  // all LDS reads done; no loads in flight (last iter staged none)

  // ---- epilogue: stage C through LDS, coalesced stores
  if (!OF32) {
    unsigned short* C = (unsigned short*)Cv;
    #pragma unroll
    for (int j = 0; j < 4; j++) {
      int col = wn + j * 16 + m16;
      #pragma unroll
      for (int i = 0; i < 4; i++)
        #pragma unroll
        for (int r = 0; r < 4; r++)
          sh[(wm + i * 16 + quad * 4 + r) * 128 + col] = (short)f2bf(acc[i][j][r]);
    }
    __syncthreads();
    #pragma unroll
    for (int c = 0; c < 8; c++) {
      int idx = c * 256 + t;
      int row = idx >> 4, col = (idx & 15) * 8;
      if (bm + row < Mvalid)
        *(uint4*)(&C[(size_t)(bm + row) * Nn + bn + col]) = *(const uint4*)(&sh[row * 128 + col]);
    }
  } else {
    float* Cf = (float*)Cv;
    float* shf = (float*)sh;  // 128 x 128 f32 = 64KB, single pass
    #pragma unroll
    for (int j = 0; j < 4; j++) {
      int col = wn + j * 16 + m16;
      float bv = bias ? bias[bn + col] : 0.f;
      #pragma unroll
      for (int i = 0; i < 4; i++)
        #pragma unroll
        for (int r = 0; r < 4; r++)
          shf[(wm + i * 16 + quad * 4 + r) * 128 + col] = acc[i][j][r] + bv;
    }
    __syncthreads();
    #pragma unroll
    for (int c = 0; c < 16; c++) {
      int idx = c * 256 + t;
      int row = idx >> 5, col = (idx & 31) * 4;
      if (bm + row < Mvalid)
        *(float4*)(&Cf[(size_t)(bm + row) * Nn + bn + col]) =
            *(const float4*)(&shf[row * 128 + col]);
    }
  }
}

// ---------------- block-wide sum helper ----------------
__device__ __forceinline__ float block_sum(float v, float* red) {
  int t = threadIdx.x;
  red[t] = v;
  __syncthreads();
  for (int st = 128; st > 0; st >>= 1) {
    if (t < st) red[t] += red[t + st];
    __syncthreads();
  }
  float r = red[0];
  __syncthreads();
  return r;
}

// ---------------- fused attention: blocks 0..767 = main rows (MFMA), ----------
// blocks 768..863 = CLS row. Paths are blockIdx-uniform; LDS overlaid on one
// 37888B pool (main: ps|ks|vs|tailbuf; cls: s|red|q|pvred). CLS blocks dispatch
// last and fill the 4th-block/CU LDS slot + the main grid's tail -> the CLS
// kernel's standalone duration and one launch gap are absorbed.
// Main path (verbatim round-2-verified): S^T = K.Q^T via mfma; P in PV A-layout
// via b64 LDS writes; V^T staged per tile; SCALE pre-folded into Q; l via
// ones-MFMA; K/V register-prefetched one tile ahead; 16 tiles + key-1024 tail.
__global__ __launch_bounds__(256) void attn_fused(
    const unsigned short* __restrict__ qkv, const float* __restrict__ canny,
    const float* __restrict__ noise, unsigned short* __restrict__ attn_out) {
  __shared__ __align__(16) char pool[37888];
  int id = blockIdx.x;
  int t = threadIdx.x;

  if (id < 768) {
    // ================= main path =================
    short* ps = (short*)pool;                          // 128*72 shorts
    short* ks = (short*)(pool + 18432);                // 64*72 shorts
    unsigned int* vs = (unsigned int*)(pool + 27648);  // 64*36 words
    float* tailbuf = (float*)(pool + 36864);           // 256 floats

    int tile = id / 96;
    int rem = id % 96;
    int h = rem >> 3;
    int b = rem & 7;
    int lane = t & 63, w = t >> 6;
    int m16 = lane & 15, quad = lane >> 4;

    int qbase = 1 + tile * 128;

    // ---- stage Q (each wave stages exactly its own 32 rows)
    {
      int r = t >> 1, seg = (t & 1) * 32;
      const uint4* src = (const uint4*)(qkv + (size_t)(b * N_ + qbase + r) * QKVC_ + h * 64 + seg);
      uint4 u0 = src[0], u1 = src[1], u2 = src[2], u3 = src[3];
      *(uint4*)(&ps[r * 72 + seg])      = u0;
      *(uint4*)(&ps[r * 72 + seg + 8])  = u1;
      *(uint4*)(&ps[r * 72 + seg + 16]) = u2;
      *(uint4*)(&ps[r * 72 + seg + 24]) = u3;
    }
    // ---- Q B-operand fragments, pre-scaled by SCALE_ (so P = __expf(s) later)
    s16x8 qb[2][2];
    #pragma unroll
    for (int nt = 0; nt < 2; nt++)
      #pragma unroll
      for (int ks_ = 0; ks_ < 2; ks_++) {
        qb[nt][ks_] = *(const s16x8*)(&ps[(w * 32 + nt * 16 + m16) * 72 + ks_ * 32 + quad * 8]);
        unsigned int* u = (unsigned int*)&qb[nt][ks_];
        #pragma unroll
        for (int i = 0; i < 4; i++)
          u[i] = pkbf2(blo(u[i]) * SCALE_, bhi(u[i]) * SCALE_);
      }
    // ones fragment for row-sum MFMA
    s16x8 vone;
    #pragma unroll
    for (int i = 0; i < 8; i++) vone[i] = (short)0x3F80;

    f32x4 oacc[2][4], lacc[2];
    #pragma unroll
    for (int mt = 0; mt < 2; mt++) {
      lacc[mt] = (f32x4){0.f, 0.f, 0.f, 0.f};
      #pragma unroll
      for (int dt = 0; dt < 4; dt++) oacc[mt][dt] = (f32x4){0.f, 0.f, 0.f, 0.f};
    }

    // ---- prefetch addressing
    int kkey = t >> 2, kseg = (t & 3) * 16;
    const unsigned short* kbase = qkv + (size_t)(b * N_) * QKVC_ + D_ + h * 64;
    int vp2 = t & 31, vseg = t >> 5;
    const unsigned short* vbase = qkv + (size_t)(b * N_) * QKVC_ + 2 * D_ + h * 64 + vseg * 8;
    uint4 kr0, kr1, vr0, vr1;
    {
      const uint4* ksrc = (const uint4*)(kbase + (size_t)kkey * QKVC_ + kseg);
      kr0 = ksrc[0]; kr1 = ksrc[1];
      vr0 = *(const uint4*)(vbase + (size_t)(2 * vp2) * QKVC_);
      vr1 = *(const uint4*)(vbase + (size_t)(2 * vp2 + 1) * QKVC_);
    }

    for (int jt = 0; jt < 16; jt++) {
      __syncthreads();  // prior QK(ks)/PV(vs) reads complete
      // ---- write prefetched K tile [key][hd]
      *(uint4*)(&ks[kkey * 72 + kseg])     = kr0;
      *(uint4*)(&ks[kkey * 72 + kseg + 8]) = kr1;
      // ---- write prefetched V^T tile [dim][keypair] (perm pack)
      {
        const unsigned int* vaw = (const unsigned int*)&vr0;
        const unsigned int* vbw = (const unsigned int*)&vr1;
        #pragma unroll
        for (int i = 0; i < 4; i++) {
          vs[(vseg * 8 + 2 * i)     * 36 + vp2] = __builtin_amdgcn_perm(vbw[i], vaw[i], 0x05040100u);
          vs[(vseg * 8 + 2 * i + 1) * 36 + vp2] = __builtin_amdgcn_perm(vbw[i], vaw[i], 0x07060302u);
        }
      }
      __syncthreads();  // staging visible (no global loads in flight here)
      // ---- issue next tile's loads; they overlap QK+exp, drain at next barrier
      if (jt < 15) {
        int j0 = (jt + 1) * 64;
        const uint4* ksrc = (const uint4*)(kbase + (size_t)(j0 + kkey) * QKVC_ + kseg);
        kr0 = ksrc[0]; kr1 = ksrc[1];
        vr0 = *(const uint4*)(vbase + (size_t)(j0 + 2 * vp2) * QKVC_);
        vr1 = *(const uint4*)(vbase + (size_t)(j0 + 2 * vp2 + 1) * QKVC_);
      }
      // ---- QK: S^T[key][qrow] per wave: 4 key-tiles x 2 row-tiles
      f32x4 sacc[4][2];
      #pragma unroll
      for (int kt = 0; kt < 4; kt++) {
        s16x8 ka0 = *(const s16x8*)(&ks[(kt * 16 + m16) * 72 + quad * 8]);
        s16x8 ka1 = *(const s16x8*)(&ks[(kt * 16 + m16) * 72 + 32 + quad * 8]);
        #pragma unroll
        for (int nt = 0; nt < 2; nt++) {
          f32x4 s = (f32x4){0.f, 0.f, 0.f, 0.f};
          s = __builtin_amdgcn_mfma_f32_16x16x32_bf16(ka0, qb[nt][0], s, 0, 0, 0);
          s = __builtin_amdgcn_mfma_f32_16x16x32_bf16(ka1, qb[nt][1], s, 0, 0, 0);
          sacc[kt][nt] = s;
        }
      }
      // ---- P = exp(s) (scale pre-folded); perm-pack 4 keys -> b64 write
      #pragma unroll
      for (int kt = 0; kt < 4; kt++) {
        #pragma unroll
        for (int nt = 0; nt < 2; nt++) {
          f32x4 s = sacc[kt][nt];
          float p0 = __expf(s[0]);
          float p1 = __expf(s[1]);
          float p2 = __expf(s[2]);
          float p3 = __expf(s[3]);
          uint2 pk = {pkbf2(p0, p1), pkbf2(p2, p3)};
          *(uint2*)(&ps[(w * 32 + nt * 16 + m16) * 72 + kt * 16 + quad * 4]) = pk;
        }
      }
      __syncthreads();  // ps visible; prefetch loads drained here (overlapped)
      // ---- PV: O += P·V ; l += P·1 (C-layout row-sums)
      s16x8 pa[2][2];
      #pragma unroll
      for (int mt = 0; mt < 2; mt++)
        #pragma unroll
        for (int ks_ = 0; ks_ < 2; ks_++)
          pa[mt][ks_] = *(const s16x8*)(&ps[(w * 32 + mt * 16 + m16) * 72 + ks_ * 32 + quad * 8]);
      const short* vss = (const short*)vs;
      #pragma unroll
      for (int dt = 0; dt < 4; dt++) {
        s16x8 vb0 = *(const s16x8*)(&vss[(dt * 16 + m16) * 72 + quad * 8]);
        s16x8 vb1 = *(const s16x8*)(&vss[(dt * 16 + m16) * 72 + 32 + quad * 8]);
        #pragma unroll
        for (int mt = 0; mt < 2; mt++) {
          oacc[mt][dt] = __builtin_amdgcn_mfma_f32_16x16x32_bf16(pa[mt][0], vb0, oacc[mt][dt], 0, 0, 0);
          oacc[mt][dt] = __builtin_amdgcn_mfma_f32_16x16x32_bf16(pa[mt][1], vb1, oacc[mt][dt], 0, 0, 0);
        }
      }
      #pragma unroll
      for (int mt = 0; mt < 2; mt++) {
        lacc[mt] = __builtin_amdgcn_mfma_f32_16x16x32_bf16(pa[mt][0], vone, lacc[mt], 0, 0, 0);
        lacc[mt] = __builtin_amdgcn_mfma_f32_16x16x32_bf16(pa[mt][1], vone, lacc[mt], 0, 0, 0);
      }
    }
    // ---- tail: key 1024 (q fragments pre-scaled -> p = expf(d))
    if (t < 64)       tailbuf[t]             = bf2f(qkv[(size_t)(b * N_ + 1024) * QKVC_ + D_     + h * 64 + t]);
    else if (t < 128) tailbuf[64 + (t - 64)] = bf2f(qkv[(size_t)(b * N_ + 1024) * QKVC_ + 2 * D_ + h * 64 + (t - 64)]);
    __syncthreads();
    #pragma unroll
    for (int nt = 0; nt < 2; nt++) {
      float d = 0.f;
      #pragma unroll
      for (int jj = 0; jj < 8; jj++) {
        d += bf2f((unsigned short)qb[nt][0][jj]) * tailbuf[quad * 8 + jj];
        d += bf2f((unsigned short)qb[nt][1][jj]) * tailbuf[32 + quad * 8 + jj];
      }
      d += __shfl_xor(d, 16, 64);
      d += __shfl_xor(d, 32, 64);
      float p = __expf(d);
      if (quad == 0) tailbuf[128 + w * 32 + nt * 16 + m16] = p;
    }
    __syncthreads();
    #pragma unroll
    for (int mt = 0; mt < 2; mt++)
      #pragma unroll
      for (int r = 0; r < 4; r++) {
        float pr = tailbuf[128 + w * 32 + mt * 16 + quad * 4 + r];
        lacc[mt][r] += pr;
        #pragma unroll
        for (int dt = 0; dt < 4; dt++)
          oacc[mt][dt][r] += pr * tailbuf[64 + dt * 16 + m16];
      }
    // ---- normalize + store (O layout: row=quad*4+r+mt*16, dim=dt*16+m16)
    #pragma unroll
    for (int mt = 0; mt < 2; mt++) {
      float rinv[4];
      #pragma unroll
      for (int r = 0; r < 4; r++) rinv[r] = 1.0f / lacc[mt][r];
      #pragma unroll
      for (int dt = 0; dt < 4; dt++) {
        #pragma unroll
        for (int r = 0; r < 4; r++) {
          int grow = b * N_ + qbase + w * 32 + mt * 16 + quad * 4 + r;
          attn_out[(size_t)grow * D_ + h * 64 + dt * 16 + m16] = f2bf(oacc[mt][dt][r] * rinv[r]);
        }
      }
    }
  } else {
    // ================= CLS path (row 0 of each (b,h)) =================
    float* s     = (float*)pool;            // 1025 floats
    float* red   = (float*)(pool + 4608);   // 256
    float* q     = (float*)(pool + 5632);   // 64
    float* pvred = (float*)(pool + 5888);   // 64*33 floats (+1 pad)

    int bh = id - 768;
    int b = bh / H_, h = bh % H_;

    if (t < 64) q[t] = bf2f(qkv[(size_t)(b * N_) * QKVC_ + h * 64 + t]);
    __syncthreads();

    // QK: vectorized uint4 loads (8 x 16B per key row)
    for (int j = t; j < N_; j += 256) {
      const unsigned short* krow = qkv + (size_t)(b * N_ + j) * QKVC_ + D_ + h * 64;
      float dot = 0.f;
      #pragma unroll
      for (int c = 0; c < 8; c++) {
        uint4 kk = *(const uint4*)(krow + c * 8);
        dot += q[c*8+0]*blo(kk.x) + q[c*8+1]*bhi(kk.x)
             + q[c*8+2]*blo(kk.y) + q[c*8+3]*bhi(kk.y)
             + q[c*8+4]*blo(kk.z) + q[c*8+5]*bhi(kk.z)
             + q[c*8+6]*blo(kk.w) + q[c*8+7]*bhi(kk.w);
      }
      s[j] = dot * SCALE_;
    }
    float cp = 0.f, npp = 0.f;
    for (int j = t; j < NP_; j += 256) {
      cp  += canny[b * NP_ + j] + 1.0f;
      npp += noise[b * NP_ + j];
    }
    float csum = block_sum(cp, red);
    float nsum = block_sum(npp, red);
    float e1 = 0.f;
    for (int j = t; j < N_; j += 256) if (j >= 1) e1 += __expf(s[j]);
    float sum1 = block_sum(e1, red);
    for (int j = t; j < N_; j += 256) {
      if (j >= 1) {
        s[j] = __expf(s[j]) / sum1
             + (canny[b * NP_ + j - 1] + 1.0f) / csum
             + noise[b * NP_ + j - 1] / nsum;
      }
    }
    __syncthreads();
    float e2 = 0.f;
    for (int j = t; j < N_; j += 256) { float e = __expf(s[j]); s[j] = e; e2 += e; }
    float sum2 = block_sum(e2, red);
    // PV: thread owns dim-octet o (8 dims), strides 32 rows -> 1 uint4 load/iter
    {
      int o = t & 7, g = t >> 3;
      float a[8] = {0.f, 0.f, 0.f, 0.f, 0.f, 0.f, 0.f, 0.f};
      for (int j = g; j < N_; j += 32) {
        float sv = s[j];
        uint4 vv = *(const uint4*)(qkv + (size_t)(b * N_ + j) * QKVC_ + 2 * D_ + h * 64 + o * 8);
        a[0] += sv * blo(vv.x); a[1] += sv * bhi(vv.x);
        a[2] += sv * blo(vv.y); a[3] += sv * bhi(vv.y);
        a[4] += sv * blo(vv.z); a[5] += sv * bhi(vv.z);
        a[6] += sv * blo(vv.w); a[7] += sv * bhi(vv.w);
      }
      #pragma unroll
      for (int i = 0; i < 8; i++) pvred[(o * 8 + i) * 33 + g] = a[i];
    }
    __syncthreads();
    if (t < 64) {
      float acc = 0.f;
      #pragma unroll
      for (int u = 0; u < 32; u++) acc += pvred[t * 33 + u];
      attn_out[(size_t)(b * N_) * D_ + h * 64 + t] = f2bf(acc / sum2);
    }
  }
}

// ---------------- launch ----------------
extern "C" void kernel_launch(void* const* d_in, const int* in_sizes, int n_in,
                              void* d_out, int out_size, void* d_ws, size_t ws_size,
                              hipStream_t stream) {
  (void)in_sizes; (void)n_in; (void)out_size; (void)ws_size;
  const float* x     = (const float*)d_in[0];
  const float* canny = (const float*)d_in[1];
  const float* noise = (const float*)d_in[2];
  const float* lnw   = (const float*)d_in[3];
  const float* lnb   = (const float*)d_in[4];
  const float* wqkv  = (const float*)d_in[5];
  const float* wout  = (const float*)d_in[6];
  const float* bout  = (const float*)d_in[7];
  float* out = (float*)d_out;
  char* ws = (char*)d_ws;

  unsigned short* xn    = (unsigned short*)(ws);              // 8320*768 bf16 (reused as attn_out)
  unsigned short* wqkvT = (unsigned short*)(ws + 12779520);   // 2304*768
  unsigned short* woutT = (unsigned short*)(ws + 16318464);   // 768*768
  unsigned short* qkv   = (unsigned short*)(ws + 17498112);   // 8200*2304

  transpose_f2b2<<<dim3(96, 24), 256, 0, stream>>>(wqkv, wqkvT, wout, woutT);
  layernorm_k<<<dim3(ROWS_), 192, 0, stream>>>(x, lnw, lnb, xn);
  gemm_bt<false><<<dim3((QKVC_ / 128) * (ROWS_PAD_ / 128)), 256, 0, stream>>>(
      xn, wqkvT, (void*)qkv, nullptr, ROWS_, QKVC_, D_);
  attn_fused<<<dim3(768 + B_ * H_), 256, 0, stream>>>(qkv, canny, noise, xn);
  gemm_bt<true><<<dim3((D_ / 128) * (ROWS_PAD_ / 128)), 256, 0, stream>>>(
      xn, woutT, (void*)out, bout, ROWS_, D_, D_);
}

// Round 9
// 205.353 us; speedup vs baseline: 1.1208x; 1.0080x over previous
//
#include <hip/hip_runtime.h>

#define B_ 8
#define N_ 1025
#define D_ 768
#define H_ 12
#define NP_ 1024
#define ROWS_ (B_*N_)        /* 8200 */
#define ROWS_PAD_ 8320       /* 65*128 */
#define QKVC_ 2304
#define SCALE_ 0.03608439182435161f  /* 768^-0.5 */
#define EPS_ 1e-5f

typedef float f32x4 __attribute__((ext_vector_type(4)));
typedef short s16x8 __attribute__((ext_vector_type(8)));

// async global->LDS, 16B per lane; lds dest must be wave-uniform base + lane*16
#define GLD16(g, l) __builtin_amdgcn_global_load_lds( \
    (const __attribute__((address_space(1))) unsigned int*)(g), \
    (__attribute__((address_space(3))) unsigned int*)(l), 16, 0, 0)

__device__ __forceinline__ float blo(unsigned int u){
  union { unsigned int i; float f; } v; v.i = u << 16; return v.f;
}
__device__ __forceinline__ float bhi(unsigned int u){
  union { unsigned int i; float f; } v; v.i = u & 0xffff0000u; return v.f;
}
__device__ __forceinline__ float bf2f(unsigned short u){
  union { unsigned int i; float f; } v; v.i = ((unsigned int)u) << 16; return v.f;
}
__device__ __forceinline__ unsigned short f2bf(float f){
  union { unsigned int i; float f; } v; v.f = f;
  unsigned int b = v.i;
  b = b + 0x7fffu + ((b >> 16) & 1u);
  return (unsigned short)(b >> 16);
}
// pack two f32 -> two bf16 (round-half-up, bit-identical to f2bf pairs), 3 VALU.
// NOTE (r4/r7/r8 post-mortem): do NOT replace with inline-asm v_cvt_pk_bf16_f32
// when inputs come from __expf/v_exp_f32 -- the TRANS-op latency hazard is not
// fenced ahead of INLINEASM consumers and reads stale registers (absmax ~1.4e-2
// in three independent builds). pkbf2 uses compiler-visible ops -> hazard handled.
__device__ __forceinline__ unsigned int pkbf2(float a, float b){
  union { float f; unsigned int i; } ua, ub;
  ua.f = a; ub.f = b;
  return __builtin_amdgcn_perm(ub.i + 0x8000u, ua.i + 0x8000u, 0x07060302u);
}

// ---------------- prep: fused weight transposes + layernorm ----------------
// blocks 0..2303: transpose (768 x N) fp32 -> (N x 768) bf16 (two weights)
// blocks 2304..10503: layernorm row (id-2304), 192 active lanes, float4 loads
__global__ __launch_bounds__(256) void prep_fused(
    const float* __restrict__ w1, unsigned short* __restrict__ d1,
    const float* __restrict__ w2, unsigned short* __restrict__ d2,
    const float* __restrict__ x, const float* __restrict__ lw,
    const float* __restrict__ lb, unsigned short* __restrict__ xn) {
  int id = blockIdx.x;
  int t = threadIdx.x;
  if (id < 2304) {
    __shared__ unsigned short tile[32][33];
    int bx = id % 96;
    int kb = (id / 96) * 32;
    const float* src; unsigned short* dst; int N, nb;
    if (bx < 72) { src = w1; dst = d1; N = QKVC_; nb = bx * 32; }
    else         { src = w2; dst = d2; N = D_;    nb = (bx - 72) * 32; }
    int tx = t & 31, ty = t >> 5;  // 32 x 8
    #pragma unroll
    for (int i = 0; i < 4; i++) {
      int r = ty + i * 8;
      tile[r][tx] = f2bf(src[(size_t)(kb + r) * N + nb + tx]);
    }
    __syncthreads();
    #pragma unroll
    for (int i = 0; i < 4; i++) {
      int r = ty + i * 8;
      dst[(size_t)(nb + r) * D_ + kb + tx] = tile[tx][r];
    }
  } else {
    int row = id - 2304;
    __shared__ float r6[6];
    float4 v; float s = 0.f, q = 0.f;
    if (t < 192) {
      v = ((const float4*)(x + (size_t)row * D_))[t];
      s = v.x + v.y + v.z + v.w;
      q = v.x * v.x + v.y * v.y + v.z * v.z + v.w * v.w;
      #pragma unroll
      for (int off = 32; off > 0; off >>= 1) {
        s += __shfl_xor(s, off, 64);
        q += __shfl_xor(q, off, 64);
      }
      if ((t & 63) == 0) { r6[t >> 6] = s; r6[3 + (t >> 6)] = q; }
    }
    __syncthreads();
    if (t < 192) {
      s = r6[0] + r6[1] + r6[2];
      q = r6[3] + r6[4] + r6[5];
      float mean = s * (1.0f / 768.0f);
      float var = q * (1.0f / 768.0f) - mean * mean;
      var = var < 0.f ? 0.f : var;
      float rstd = rsqrtf(var + EPS_);
      float4 wv4 = ((const float4*)lw)[t];
      float4 bv4 = ((const float4*)lb)[t];
      float o0 = (v.x - mean) * rstd * wv4.x + bv4.x;
      float o1 = (v.y - mean) * rstd * wv4.y + bv4.y;
      float o2 = (v.z - mean) * rstd * wv4.z + bv4.z;
      float o3 = (v.w - mean) * rstd * wv4.w + bv4.w;
      uint2 pk = {pkbf2(o0, o1), pkbf2(o2, o3)};
      *(uint2*)(xn + (size_t)row * D_ + t * 4) = pk;
    }
  }
}

// ---------------- GEMM: C[M][N] = A[M][K] * Bt[N][K]^T (+bias)
// 128x128 tile, 256 thr / 4 waves (2Mx2N), wave tile 64x64, BK=64.
// Double-buffered LDS = 64KB (2 blocks/CU co-resident -> TLP preserved).
// Minimum-2-phase pipeline: ONE vmcnt(0)+s_barrier per K-tile; next tile's 8
// global_load_lds issued BEFORE compute so they overlap the full MFMA phase.
// T2 swizzle: [128 rows][64 k] = 8x16B granules/row; LDS linear, global source
// k-granule = slot ^ (row&7); fragment read granule (ks*4+quad)^(m16&7) ->
// every granule-base hit by exactly 2 lanes = free. T1 bijective XCD swizzle.
// NOTE (r2 post-mortem): at 128^2 the per-K-step L2 operand traffic (64KB/CU)
// bounds MfmaUtil at ~27%; we measure 24%. Near structural ceiling for this tile.
template <bool OF32>
__global__ __launch_bounds__(256) void gemm_bt(
    const unsigned short* __restrict__ A, const unsigned short* __restrict__ Bt,
    void* __restrict__ Cv, const float* __restrict__ bias,
    int Mvalid, int Nn, int Kk) {
  __shared__ short sh[32768];  // 64KB: As[2][8192] | Bs[2][8192]; reused as C-stage
  int t = threadIdx.x;
  int lane = t & 63, w = t >> 6;
  int m16 = lane & 15, quad = lane >> 4;

  // bijective XCD swizzle (m204): consecutive wg on one XCD share the A panel
  int nwg = gridDim.x;
  int nbx = Nn >> 7;
  int id = blockIdx.x;
  int qq = nwg >> 3, rr = nwg & 7;
  int xcd = id & 7, off = id >> 3;
  int wg = (xcd < rr ? xcd * (qq + 1) : rr * (qq + 1) + (xcd - rr) * qq) + off;
  int bx = wg % nbx, by = wg / nbx;
  int bm = by * 128, bn = bx * 128;

  int wm = (w & 1) * 64, wn = (w >> 1) * 64;

  f32x4 acc[4][4];
  #pragma unroll
  for (int i = 0; i < 4; i++)
    #pragma unroll
    for (int j = 0; j < 4; j++) acc[i][j] = (f32x4){0.f, 0.f, 0.f, 0.f};

  // staging: thread owns granules g = t + c*256 (c=0..3) of each 16KB tile.
  // LDS dest linear (granule g at shorts g*8); global src pre-swizzled.
  const unsigned short* aP[4];
  const unsigned short* bP[4];
  #pragma unroll
  for (int c = 0; c < 4; c++) {
    int g = t + c * 256;
    int row = g >> 3, slot = g & 7;
    aP[c] = A  + (size_t)(bm + row) * Kk + ((slot ^ (row & 7)) * 8);
    bP[c] = Bt + (size_t)(bn + row) * Kk + ((slot ^ (row & 7)) * 8);
  }

  int KS = Kk >> 6;  // 12
  int cur = 0;
  // prologue: stage tile 0 into buf 0
  #pragma unroll
  for (int c = 0; c < 4; c++) GLD16(aP[c], sh + (t + c * 256) * 8);
  #pragma unroll
  for (int c = 0; c < 4; c++) GLD16(bP[c], sh + 16384 + (t + c * 256) * 8);

  for (int kt = 0; kt < KS; kt++) {
    // wait own 8 loads of tile kt; barrier -> ALL waves' tile-kt data in LDS,
    // and all waves done reading buf^1 (last read in iter kt-1) -> safe to stage.
    asm volatile("s_waitcnt vmcnt(0)" ::: "memory");
    __builtin_amdgcn_s_barrier();
    if (kt + 1 < KS) {
      int nb2 = (cur ^ 1) * 8192;
      int ko = (kt + 1) * 64;
      #pragma unroll
      for (int c = 0; c < 4; c++) GLD16(aP[c] + ko, sh + nb2 + (t + c * 256) * 8);
      #pragma unroll
      for (int c = 0; c < 4; c++) GLD16(bP[c] + ko, sh + 16384 + nb2 + (t + c * 256) * 8);
    }
    const short* sa = sh + cur * 8192;
    const short* sb = sh + 16384 + cur * 8192;
    #pragma unroll
    for (int ks = 0; ks < 2; ks++) {
      int so = ((ks * 4 + quad) ^ (m16 & 7)) * 8;
      s16x8 af[4], bfr[4];
      #pragma unroll
      for (int i = 0; i < 4; i++) {
        af[i]  = *(const s16x8*)(sa + (wm + i * 16 + m16) * 64 + so);
        bfr[i] = *(const s16x8*)(sb + (wn + i * 16 + m16) * 64 + so);
      }
      __builtin_amdgcn_s_setprio(1);
      #pragma unroll
      for (int i = 0; i < 4; i++)
        #pragma unroll
        for (int j = 0; j < 4; j++)
          acc[i][j] = __builtin_amdgcn_mfma_f32_16x16x32_bf16(af[i], bfr[j], acc[i][j], 0, 0, 0);
      __builtin_amdgcn_s_setprio(0);
    }
    cur ^= 1;
  }
  __syncthreads();  // all LDS reads done; no loads in flight (last iter staged none)

  // ---- epilogue: stage C through LDS, coalesced stores
  if (!OF32) {
    unsigned short* C = (unsigned short*)Cv;
    #pragma unroll
    for (int j = 0; j < 4; j++) {
      int col = wn + j * 16 + m16;
      #pragma unroll
      for (int i = 0; i < 4; i++)
        #pragma unroll
        for (int r = 0; r < 4; r++)
          sh[(wm + i * 16 + quad * 4 + r) * 128 + col] = (short)f2bf(acc[i][j][r]);
    }
    __syncthreads();
    #pragma unroll
    for (int c = 0; c < 8; c++) {
      int idx = c * 256 + t;
      int row = idx >> 4, col = (idx & 15) * 8;
      if (bm + row < Mvalid)
        *(uint4*)(&C[(size_t)(bm + row) * Nn + bn + col]) = *(const uint4*)(&sh[row * 128 + col]);
    }
  } else {
    float* Cf = (float*)Cv;
    float* shf = (float*)sh;  // 128 x 128 f32 = 64KB, single pass
    #pragma unroll
    for (int j = 0; j < 4; j++) {
      int col = wn + j * 16 + m16;
      float bv = bias ? bias[bn + col] : 0.f;
      #pragma unroll
      for (int i = 0; i < 4; i++)
        #pragma unroll
        for (int r = 0; r < 4; r++)
          shf[(wm + i * 16 + quad * 4 + r) * 128 + col] = acc[i][j][r] + bv;
    }
    __syncthreads();
    #pragma unroll
    for (int c = 0; c < 16; c++) {
      int idx = c * 256 + t;
      int row = idx >> 5, col = (idx & 31) * 4;
      if (bm + row < Mvalid)
        *(float4*)(&Cf[(size_t)(bm + row) * Nn + bn + col]) =
            *(const float4*)(&shf[row * 128 + col]);
    }
  }
}

// ---------------- block-wide sum helper ----------------
__device__ __forceinline__ float block_sum(float v, float* red) {
  int t = threadIdx.x;
  red[t] = v;
  __syncthreads();
  for (int st = 128; st > 0; st >>= 1) {
    if (t < st) red[t] += red[t + st];
    __syncthreads();
  }
  float r = red[0];
  __syncthreads();
  return r;
}

// ---------------- fused attention: blocks 0..767 = main rows (MFMA), ----------
// blocks 768..863 = CLS row. Paths are blockIdx-uniform; LDS overlaid on one
// 37888B pool. Main path (r5-verified verbatim): S^T = K.Q^T via mfma; P in PV
// A-layout via b64 LDS writes; V^T staged per tile; SCALE pre-folded into Q;
// l via ones-MFMA; K/V register-prefetched one tile ahead; 16 tiles + key-1024
// tail. 3 barriers/jt. P-pack = pkbf2 (see pkbf2 note: cvtpk-after-__expf is
// a verified TRANS-hazard miscompile, r4/r7/r8).
__global__ __launch_bounds__(256) void attn_fused(
    const unsigned short* __restrict__ qkv, const float* __restrict__ canny,
    const float* __restrict__ noise, unsigned short* __restrict__ attn_out) {
  __shared__ __align__(16) char pool[37888];
  int id = blockIdx.x;
  int t = threadIdx.x;

  if (id < 768) {
    // ================= main path =================
    short* ps = (short*)pool;                          // 128*72 shorts
    short* ks = (short*)(pool + 18432);                // 64*72 shorts
    unsigned int* vs = (unsigned int*)(pool + 27648);  // 64*36 words
    float* tailbuf = (float*)(pool + 36864);           // 256 floats

    int tile = id / 96;
    int rem = id % 96;
    int h = rem >> 3;
    int b = rem & 7;
    int lane = t & 63, w = t >> 6;
    int m16 = lane & 15, quad = lane >> 4;

    int qbase = 1 + tile * 128;

    // ---- stage Q (each wave stages exactly its own 32 rows)
    {
      int r = t >> 1, seg = (t & 1) * 32;
      const uint4* src = (const uint4*)(qkv + (size_t)(b * N_ + qbase + r) * QKVC_ + h * 64 + seg);
      uint4 u0 = src[0], u1 = src[1], u2 = src[2], u3 = src[3];
      *(uint4*)(&ps[r * 72 + seg])      = u0;
      *(uint4*)(&ps[r * 72 + seg + 8])  = u1;
      *(uint4*)(&ps[r * 72 + seg + 16]) = u2;
      *(uint4*)(&ps[r * 72 + seg + 24]) = u3;
    }
    // ---- Q B-operand fragments, pre-scaled by SCALE_ (so P = __expf(s) later)
    s16x8 qb[2][2];
    #pragma unroll
    for (int nt = 0; nt < 2; nt++)
      #pragma unroll
      for (int ks_ = 0; ks_ < 2; ks_++) {
        qb[nt][ks_] = *(const s16x8*)(&ps[(w * 32 + nt * 16 + m16) * 72 + ks_ * 32 + quad * 8]);
        unsigned int* u = (unsigned int*)&qb[nt][ks_];
        #pragma unroll
        for (int i = 0; i < 4; i++)
          u[i] = pkbf2(blo(u[i]) * SCALE_, bhi(u[i]) * SCALE_);
      }
    // ones fragment for row-sum MFMA
    s16x8 vone;
    #pragma unroll
    for (int i = 0; i < 8; i++) vone[i] = (short)0x3F80;

    f32x4 oacc[2][4], lacc[2];
    #pragma unroll
    for (int mt = 0; mt < 2; mt++) {
      lacc[mt] = (f32x4){0.f, 0.f, 0.f, 0.f};
      #pragma unroll
      for (int dt = 0; dt < 4; dt++) oacc[mt][dt] = (f32x4){0.f, 0.f, 0.f, 0.f};
    }

    // ---- prefetch addressing
    int kkey = t >> 2, kseg = (t & 3) * 16;
    const unsigned short* kbase = qkv + (size_t)(b * N_) * QKVC_ + D_ + h * 64;
    int vp2 = t & 31, vseg = t >> 5;
    const unsigned short* vbase = qkv + (size_t)(b * N_) * QKVC_ + 2 * D_ + h * 64 + vseg * 8;
    uint4 kr0, kr1, vr0, vr1;
    {
      const uint4* ksrc = (const uint4*)(kbase + (size_t)kkey * QKVC_ + kseg);
      kr0 = ksrc[0]; kr1 = ksrc[1];
      vr0 = *(const uint4*)(vbase + (size_t)(2 * vp2) * QKVC_);
      vr1 = *(const uint4*)(vbase + (size_t)(2 * vp2 + 1) * QKVC_);
    }

    for (int jt = 0; jt < 16; jt++) {
      __syncthreads();  // prior QK(ks)/PV(vs) reads complete
      // ---- write prefetched K tile [key][hd]
      *(uint4*)(&ks[kkey * 72 + kseg])     = kr0;
      *(uint4*)(&ks[kkey * 72 + kseg + 8]) = kr1;
      // ---- write prefetched V^T tile [dim][keypair] (perm pack)
      {
        const unsigned int* vaw = (const unsigned int*)&vr0;
        const unsigned int* vbw = (const unsigned int*)&vr1;
        #pragma unroll
        for (int i = 0; i < 4; i++) {
          vs[(vseg * 8 + 2 * i)     * 36 + vp2] = __builtin_amdgcn_perm(vbw[i], vaw[i], 0x05040100u);
          vs[(vseg * 8 + 2 * i + 1) * 36 + vp2] = __builtin_amdgcn_perm(vbw[i], vaw[i], 0x07060302u);
        }
      }
      __syncthreads();  // staging visible (no global loads in flight here)
      // ---- issue next tile's loads; they overlap QK+exp, drain at next barrier
      if (jt < 15) {
        int j0 = (jt + 1) * 64;
        const uint4* ksrc = (const uint4*)(kbase + (size_t)(j0 + kkey) * QKVC_ + kseg);
        kr0 = ksrc[0]; kr1 = ksrc[1];
        vr0 = *(const uint4*)(vbase + (size_t)(j0 + 2 * vp2) * QKVC_);
        vr1 = *(const uint4*)(vbase + (size_t)(j0 + 2 * vp2 + 1) * QKVC_);
      }
      // ---- QK: S^T[key][qrow] per wave: 4 key-tiles x 2 row-tiles
      f32x4 sacc[4][2];
      #pragma unroll
      for (int kt = 0; kt < 4; kt++) {
        s16x8 ka0 = *(const s16x8*)(&ks[(kt * 16 + m16) * 72 + quad * 8]);
        s16x8 ka1 = *(const s16x8*)(&ks[(kt * 16 + m16) * 72 + 32 + quad * 8]);
        #pragma unroll
        for (int nt = 0; nt < 2; nt++) {
          f32x4 s = (f32x4){0.f, 0.f, 0.f, 0.f};
          s = __builtin_amdgcn_mfma_f32_16x16x32_bf16(ka0, qb[nt][0], s, 0, 0, 0);
          s = __builtin_amdgcn_mfma_f32_16x16x32_bf16(ka1, qb[nt][1], s, 0, 0, 0);
          sacc[kt][nt] = s;
        }
      }
      // ---- P = exp(s) (scale pre-folded); perm-pack 4 keys -> b64 write
      #pragma unroll
      for (int kt = 0; kt < 4; kt++) {
        #pragma unroll
        for (int nt = 0; nt < 2; nt++) {
          f32x4 s = sacc[kt][nt];
          float p0 = __expf(s[0]);
          float p1 = __expf(s[1]);
          float p2 = __expf(s[2]);
          float p3 = __expf(s[3]);
          uint2 pk = {pkbf2(p0, p1), pkbf2(p2, p3)};
          *(uint2*)(&ps[(w * 32 + nt * 16 + m16) * 72 + kt * 16 + quad * 4]) = pk;
        }
      }
      __syncthreads();  // ps visible; prefetch loads drained here (overlapped)
      // ---- PV: O += P·V ; l += P·1 (C-layout row-sums)
      s16x8 pa[2][2];
      #pragma unroll
      for (int mt = 0; mt < 2; mt++)
        #pragma unroll
        for (int ks_ = 0; ks_ < 2; ks_++)
          pa[mt][ks_] = *(const s16x8*)(&ps[(w * 32 + mt * 16 + m16) * 72 + ks_ * 32 + quad * 8]);
      const short* vss = (const short*)vs;
      #pragma unroll
      for (int dt = 0; dt < 4; dt++) {
        s16x8 vb0 = *(const s16x8*)(&vss[(dt * 16 + m16) * 72 + quad * 8]);
        s16x8 vb1 = *(const s16x8*)(&vss[(dt * 16 + m16) * 72 + 32 + quad * 8]);
        #pragma unroll
        for (int mt = 0; mt < 2; mt++) {
          oacc[mt][dt] = __builtin_amdgcn_mfma_f32_16x16x32_bf16(pa[mt][0], vb0, oacc[mt][dt], 0, 0, 0);
          oacc[mt][dt] = __builtin_amdgcn_mfma_f32_16x16x32_bf16(pa[mt][1], vb1, oacc[mt][dt], 0, 0, 0);
        }
      }
      #pragma unroll
      for (int mt = 0; mt < 2; mt++) {
        lacc[mt] = __builtin_amdgcn_mfma_f32_16x16x32_bf16(pa[mt][0], vone, lacc[mt], 0, 0, 0);
        lacc[mt] = __builtin_amdgcn_mfma_f32_16x16x32_bf16(pa[mt][1], vone, lacc[mt], 0, 0, 0);
      }
    }
    // ---- tail: key 1024 (q fragments pre-scaled -> p = expf(d))
    if (t < 64)       tailbuf[t]             = bf2f(qkv[(size_t)(b * N_ + 1024) * QKVC_ + D_     + h * 64 + t]);
    else if (t < 128) tailbuf[64 + (t - 64)] = bf2f(qkv[(size_t)(b * N_ + 1024) * QKVC_ + 2 * D_ + h * 64 + (t - 64)]);
    __syncthreads();
    #pragma unroll
    for (int nt = 0; nt < 2; nt++) {
      float d = 0.f;
      #pragma unroll
      for (int jj = 0; jj < 8; jj++) {
        d += bf2f((unsigned short)qb[nt][0][jj]) * tailbuf[quad * 8 + jj];
        d += bf2f((unsigned short)qb[nt][1][jj]) * tailbuf[32 + quad * 8 + jj];
      }
      d += __shfl_xor(d, 16, 64);
      d += __shfl_xor(d, 32, 64);
      float p = __expf(d);
      if (quad == 0) tailbuf[128 + w * 32 + nt * 16 + m16] = p;
    }
    __syncthreads();
    #pragma unroll
    for (int mt = 0; mt < 2; mt++)
      #pragma unroll
      for (int r = 0; r < 4; r++) {
        float pr = tailbuf[128 + w * 32 + mt * 16 + quad * 4 + r];
        lacc[mt][r] += pr;
        #pragma unroll
        for (int dt = 0; dt < 4; dt++)
          oacc[mt][dt][r] += pr * tailbuf[64 + dt * 16 + m16];
      }
    // ---- normalize + store (O layout: row=quad*4+r+mt*16, dim=dt*16+m16)
    #pragma unroll
    for (int mt = 0; mt < 2; mt++) {
      float rinv[4];
      #pragma unroll
      for (int r = 0; r < 4; r++) rinv[r] = 1.0f / lacc[mt][r];
      #pragma unroll
      for (int dt = 0; dt < 4; dt++) {
        #pragma unroll
        for (int r = 0; r < 4; r++) {
          int grow = b * N_ + qbase + w * 32 + mt * 16 + quad * 4 + r;
          attn_out[(size_t)grow * D_ + h * 64 + dt * 16 + m16] = f2bf(oacc[mt][dt][r] * rinv[r]);
        }
      }
    }
  } else {
    // ================= CLS path (row 0 of each (b,h)) =================
    float* s     = (float*)pool;            // 1025 floats
    float* red   = (float*)(pool + 4608);   // 256
    float* q     = (float*)(pool + 5632);   // 64
    float* pvred = (float*)(pool + 5888);   // 64*33 floats (+1 pad)

    int bh = id - 768;
    int b = bh / H_, h = bh % H_;

    if (t < 64) q[t] = bf2f(qkv[(size_t)(b * N_) * QKVC_ + h * 64 + t]);
    __syncthreads();

    // QK: vectorized uint4 loads (8 x 16B per key row)
    for (int j = t; j < N_; j += 256) {
      const unsigned short* krow = qkv + (size_t)(b * N_ + j) * QKVC_ + D_ + h * 64;
      float dot = 0.f;
      #pragma unroll
      for (int c = 0; c < 8; c++) {
        uint4 kk = *(const uint4*)(krow + c * 8);
        dot += q[c*8+0]*blo(kk.x) + q[c*8+1]*bhi(kk.x)
             + q[c*8+2]*blo(kk.y) + q[c*8+3]*bhi(kk.y)
             + q[c*8+4]*blo(kk.z) + q[c*8+5]*bhi(kk.z)
             + q[c*8+6]*blo(kk.w) + q[c*8+7]*bhi(kk.w);
      }
      s[j] = dot * SCALE_;
    }
    float cp = 0.f, npp = 0.f;
    for (int j = t; j < NP_; j += 256) {
      cp  += canny[b * NP_ + j] + 1.0f;
      npp += noise[b * NP_ + j];
    }
    float csum = block_sum(cp, red);
    float nsum = block_sum(npp, red);
    float e1 = 0.f;
    for (int j = t; j < N_; j += 256) if (j >= 1) e1 += __expf(s[j]);
    float sum1 = block_sum(e1, red);
    for (int j = t; j < N_; j += 256) {
      if (j >= 1) {
        s[j] = __expf(s[j]) / sum1
             + (canny[b * NP_ + j - 1] + 1.0f) / csum
             + noise[b * NP_ + j - 1] / nsum;
      }
    }
    __syncthreads();
    float e2 = 0.f;
    for (int j = t; j < N_; j += 256) { float e = __expf(s[j]); s[j] = e; e2 += e; }
    float sum2 = block_sum(e2, red);
    // PV: thread owns dim-octet o (8 dims), strides 32 rows -> 1 uint4 load/iter
    {
      int o = t & 7, g = t >> 3;
      float a[8] = {0.f, 0.f, 0.f, 0.f, 0.f, 0.f, 0.f, 0.f};
      for (int j = g; j < N_; j += 32) {
        float sv = s[j];
        uint4 vv = *(const uint4*)(qkv + (size_t)(b * N_ + j) * QKVC_ + 2 * D_ + h * 64 + o * 8);
        a[0] += sv * blo(vv.x); a[1] += sv * bhi(vv.x);
        a[2] += sv * blo(vv.y); a[3] += sv * bhi(vv.y);
        a[4] += sv * blo(vv.z); a[5] += sv * bhi(vv.z);
        a[6] += sv * blo(vv.w); a[7] += sv * bhi(vv.w);
      }
      #pragma unroll
      for (int i = 0; i < 8; i++) pvred[(o * 8 + i) * 33 + g] = a[i];
    }
    __syncthreads();
    if (t < 64) {
      float acc = 0.f;
      #pragma unroll
      for (int u = 0; u < 32; u++) acc += pvred[t * 33 + u];
      attn_out[(size_t)(b * N_) * D_ + h * 64 + t] = f2bf(acc / sum2);
    }
  }
}

// ---------------- launch ----------------
extern "C" void kernel_launch(void* const* d_in, const int* in_sizes, int n_in,
                              void* d_out, int out_size, void* d_ws, size_t ws_size,
                              hipStream_t stream) {
  (void)in_sizes; (void)n_in; (void)out_size; (void)ws_size;
  const float* x     = (const float*)d_in[0];
  const float* canny = (const float*)d_in[1];
  const float* noise = (const float*)d_in[2];
  const float* lnw   = (const float*)d_in[3];
  const float* lnb   = (const float*)d_in[4];
  const float* wqkv  = (const float*)d_in[5];
  const float* wout  = (const float*)d_in[6];
  const float* bout  = (const float*)d_in[7];
  float* out = (float*)d_out;
  char* ws = (char*)d_ws;

  unsigned short* xn    = (unsigned short*)(ws);              // 8320*768 bf16 (reused as attn_out)
  unsigned short* wqkvT = (unsigned short*)(ws + 12779520);   // 2304*768
  unsigned short* woutT = (unsigned short*)(ws + 16318464);   // 768*768
  unsigned short* qkv   = (unsigned short*)(ws + 17498112);   // 8200*2304

  prep_fused<<<dim3(2304 + ROWS_), 256, 0, stream>>>(
      wqkv, wqkvT, wout, woutT, x, lnw, lnb, xn);
  gemm_bt<false><<<dim3((QKVC_ / 128) * (ROWS_PAD_ / 128)), 256, 0, stream>>>(
      xn, wqkvT, (void*)qkv, nullptr, ROWS_, QKVC_, D_);
  attn_fused<<<dim3(768 + B_ * H_), 256, 0, stream>>>(qkv, canny, noise, xn);
  gemm_bt<true><<<dim3((D_ / 128) * (ROWS_PAD_ / 128)), 256, 0, stream>>>(
      xn, woutT, (void*)out, bout, ROWS_, D_, D_);
}